// Round 7
// baseline (226.057 us; speedup 1.0000x reference)
//
#include <hip/hip_runtime.h>
#include <math.h>

#define B_   64
#define S_   197
#define D_   768
#define H_   12
#define HD_  64
#define M_   (B_ * S_)     // 12608
#define MPAD 12672         // 99*128
#define KE   224           // padded contraction length over s (7*32)
#define BH_  (B_ * H_)     // 768
#define WSZ  ((size_t)D_ * D_)   // 589824

typedef _Float16 half8_t __attribute__((ext_vector_type(8)));
typedef _Float16 half4_t __attribute__((ext_vector_type(4)));
typedef _Float16 half2_t __attribute__((ext_vector_type(2)));
typedef float floatx4 __attribute__((ext_vector_type(4)));

// async global->LDS DMA, 16B per lane; lptr must be wave-uniform (HW adds lane*16)
#define LDS_DMA16(gptr, lptr) \
  __builtin_amdgcn_global_load_lds((const __attribute__((address_space(1))) void*)(gptr), \
                                   (__attribute__((address_space(3))) void*)(lptr), 16, 0, 0)

// ---------------------------------------------------------------------------
// Fused prep: [0,9504) X->fp16 (zero-pad rows to MPAD); [9504,11808) weight
// transpose+convert (Wk,Wv,Wq -> Tcat, Wo -> To); [11808,11810) E_k/E_v ->
// EET rows [0,64)/[64,128) as [r][KE] fp16 (zero-padded s>=197) + esum[r].
// ---------------------------------------------------------------------------
__global__ __launch_bounds__(256) void prep_kernel(
    const float* __restrict__ X,
    const float* __restrict__ Wq, const float* __restrict__ Wk,
    const float* __restrict__ Wv, const float* __restrict__ Wo,
    const float* __restrict__ Ek, const float* __restrict__ Ev,
    _Float16* __restrict__ Xh,
    _Float16* __restrict__ Tcat, _Float16* __restrict__ To,
    _Float16* __restrict__ EET,
    float* __restrict__ esumK, float* __restrict__ esumV)
{
    __shared__ float tile[32][33];
    const int bid = blockIdx.x, tid = threadIdx.x;
    if (bid < 9504) {
        const int i4 = (bid * 256 + tid) * 4;
        float4 v = make_float4(0.f, 0.f, 0.f, 0.f);
        if (i4 < M_ * D_) v = *(const float4*)&X[i4];
        half4_t o = { (_Float16)v.x, (_Float16)v.y, (_Float16)v.z, (_Float16)v.w };
        *(half4_t*)&Xh[i4] = o;
        return;
    }
    int b2 = bid - 9504;
    if (b2 < 2304) {
        const int z = b2 / 576, rem = b2 % 576;
        const int bx = rem % 24, by = rem / 24;
        // z: 0->Wk, 1->Wv, 2->Wq (into Tcat), 3->Wo (into To)
        const float* W = (z == 0) ? Wk : (z == 1) ? Wv : (z == 2) ? Wq : Wo;
        _Float16* T = (z < 3) ? (Tcat + (size_t)z * WSZ) : To;
        const int n0 = bx * 32, k0 = by * 32;
        const int r = tid >> 3, c4 = (tid & 7) * 4;
        *(float4*)&tile[r][c4] = *(const float4*)&W[(size_t)(k0 + r) * D_ + n0 + c4];
        __syncthreads();
        half4_t o = { (_Float16)tile[c4 + 0][r], (_Float16)tile[c4 + 1][r],
                      (_Float16)tile[c4 + 2][r], (_Float16)tile[c4 + 3][r] };
        *(half4_t*)&T[(size_t)(n0 + r) * D_ + k0 + c4] = o;
        return;
    }
    b2 -= 2304;   // 0 -> Ek, 1 -> Ev
    const float* E = b2 ? Ev : Ek;
    _Float16* ET = EET + (size_t)b2 * 64 * KE;
    float* es = b2 ? esumV : esumK;
    for (int i = tid; i < 64 * KE; i += 256) {
        const int rr = i / KE, s = i % KE;
        ET[i] = (_Float16)((s < S_) ? E[s * 64 + rr] : 0.f);
    }
    if (tid < 64) {
        float acc = 0.f;
        for (int s = 0; s < S_; ++s) acc += E[s * 64 + tid];
        es[tid] = acc;
    }
}

// ---------------------------------------------------------------------------
// Y[b] = E^T @ X_b per batch: Ybuf rows [0,4096) = Y_k (b*64+r),
// rows [4096,8192) = Y_v.  One block per (b, 64-col tile).
// ---------------------------------------------------------------------------
__global__ __launch_bounds__(256) void y_kernel(
    const _Float16* __restrict__ Xh, const _Float16* __restrict__ EET,
    _Float16* __restrict__ Ybuf)
{
    __shared__ _Float16 Xs[KE * 66];
    const int bid = blockIdx.x;
    const int b = bid / 12, n0 = (bid % 12) * 64;
    const int tid = threadIdx.x, w = tid >> 6, lane = tid & 63;
    const int l15 = lane & 15, quad = lane >> 4;

    #pragma unroll
    for (int i = 0; i < 7; ++i) {
        const int s = i * 32 + (tid >> 3);
        const int d0 = (tid & 7) * 8;
        // rows b*197+s for s in [197,224) multiply EET's zero padding
        const half8_t v = *(const half8_t*)&Xh[(size_t)(b * S_ + s) * D_ + n0 + d0];
        #pragma unroll
        for (int jj = 0; jj < 4; ++jj) {
            half2_t t2 = { v[2 * jj], v[2 * jj + 1] };
            *(half2_t*)&Xs[s * 66 + d0 + 2 * jj] = t2;
        }
    }
    __syncthreads();

    floatx4 acc[2][4] = {};
    #pragma unroll
    for (int k7 = 0; k7 < 7; ++k7) {
        half8_t af[2];
        #pragma unroll
        for (int mi = 0; mi < 2; ++mi)
            af[mi] = *(const half8_t*)&EET[(w * 32 + mi * 16 + l15) * KE + k7 * 32 + quad * 8];
        #pragma unroll
        for (int ni = 0; ni < 4; ++ni) {
            const int sb = k7 * 32 + quad * 8;
            half8_t bf;
            #pragma unroll
            for (int jj = 0; jj < 8; ++jj) bf[jj] = Xs[(sb + jj) * 66 + ni * 16 + l15];
            #pragma unroll
            for (int mi = 0; mi < 2; ++mi)
                acc[mi][ni] = __builtin_amdgcn_mfma_f32_16x16x32_f16(
                    af[mi], bf, acc[mi][ni], 0, 0, 0);
        }
    }

    #pragma unroll
    for (int mi = 0; mi < 2; ++mi)
        #pragma unroll
        for (int ni = 0; ni < 4; ++ni)
            #pragma unroll
            for (int i = 0; i < 4; ++i) {
                const int m_local = w * 32 + mi * 16 + quad * 4 + i;
                const int row = (m_local >> 6) * 4096 + b * 64 + (m_local & 63);
                Ybuf[(size_t)row * D_ + n0 + ni * 16 + l15] = (_Float16)acc[mi][ni][i];
            }
}

// ---------------------------------------------------------------------------
// Specialized GEMM (128x128 tile, BK=32, XOR-swizzled LDS, XCD-aware map).
// LDS = 17408 B total: stage A [0,4096), B [4096,8192); epilogue transpose
// reuses [0,8704) as 4 wave-private 32x68 half-tiles (two passes of 32 rows).
// MODE 0 (624 blk): Qh = Xh@Wq^T+bq, fp16.
// MODE 1 (384 blk): m_blk<32: pk16 = Yk@Wk^T + esumK[r]*bk[n] (fp16 rows);
//                   m_blk>=32: pvT[bh][d][r] = Yv@Wv^T + esumV[r]*bv[n].
// MODE 2 (624 blk): out = CTX@Wo^T+bo, fp32 direct, guard M_ (fast path
//                   unguarded for m_blk<=97).
// ---------------------------------------------------------------------------
template<int MODE>
__global__ __launch_bounds__(256) void gemm_t(
    const _Float16* __restrict__ A,
    const _Float16* __restrict__ W0, const _Float16* __restrict__ W1,
    const float* __restrict__ b0, const float* __restrict__ b1,
    const float* __restrict__ es0, const float* __restrict__ es1,
    _Float16* __restrict__ O16a, _Float16* __restrict__ pvT,
    float* __restrict__ O32)
{
    __shared__ _Float16 sm[8704];   // 17408 B
    const int xcd = blockIdx.x & 7, t = blockIdx.x >> 3;
    const int slot = t / 6, j = t - slot * 6;
    const int m_blk = slot * 8 + xcd;
    if (MODE != 1 && m_blk >= MPAD / 128) return;
    const int m0 = m_blk * 128, n0 = j * 128;
    const bool vhalf = (MODE == 1) && (m_blk >= 32);
    const _Float16* W = vhalf ? W1 : W0;
    const float* bias = vhalf ? b1 : b0;
    const float* esum = vhalf ? es1 : es0;

    const int tid = threadIdx.x;
    const int w = tid >> 6, lane = tid & 63;
    const int fr = lane & 15, quad = lane >> 4;
    const int jrow = lane >> 2;
    const int csw = ((lane & 3) ^ ((lane >> 3) & 3)) * 8;   // swizzled src chunk
    const int ksw = (quad ^ ((fr >> 1) & 3)) * 8;           // swizzled read slot
    const int wm = (w >> 1) * 64, wn = (w & 1) * 64;

    floatx4 acc[4][4] = {};

    for (int k0 = 0; k0 < D_; k0 += 32) {
        #pragma unroll
        for (int jj = 0; jj < 2; ++jj) {
            const int r = w * 32 + jj * 16 + jrow;
            LDS_DMA16(&A[(size_t)(m0 + r) * D_ + k0 + csw],
                      &sm[w * 1024 + jj * 512]);
            LDS_DMA16(&W[(size_t)(n0 + r) * D_ + k0 + csw],
                      &sm[4096 + w * 1024 + jj * 512]);
        }
        __syncthreads();
        half8_t af[4], bf[4];
        #pragma unroll
        for (int i = 0; i < 4; ++i) {
            af[i] = *(const half8_t*)&sm[(wm + i * 16 + fr) * 32 + ksw];
            bf[i] = *(const half8_t*)&sm[4096 + (wn + i * 16 + fr) * 32 + ksw];
        }
        #pragma unroll
        for (int mi = 0; mi < 4; ++mi)
            #pragma unroll
            for (int ni = 0; ni < 4; ++ni)
                acc[mi][ni] = __builtin_amdgcn_mfma_f32_16x16x32_f16(
                    af[mi], bf[ni], acc[mi][ni], 0, 0, 0);
        __syncthreads();
    }

    float bval[4];
    #pragma unroll
    for (int ni = 0; ni < 4; ++ni)
        bval[ni] = bias[n0 + wn + ni * 16 + fr];

    if (MODE == 2) {
        const int rq = quad * 4;
        if (m0 + 128 <= M_) {
            #pragma unroll
            for (int ni = 0; ni < 4; ++ni) {
                const int n = n0 + wn + ni * 16 + fr;
                #pragma unroll
                for (int mi = 0; mi < 4; ++mi)
                    #pragma unroll
                    for (int i = 0; i < 4; ++i)
                        O32[(size_t)(m0 + wm + mi * 16 + rq + i) * D_ + n] =
                            acc[mi][ni][i] + bval[ni];
            }
        } else {
            #pragma unroll
            for (int ni = 0; ni < 4; ++ni) {
                const int n = n0 + wn + ni * 16 + fr;
                #pragma unroll
                for (int mi = 0; mi < 4; ++mi)
                    #pragma unroll
                    for (int i = 0; i < 4; ++i) {
                        const int m = m0 + wm + mi * 16 + rq + i;
                        if (m < M_)
                            O32[(size_t)m * D_ + n] = acc[mi][ni][i] + bval[ni];
                    }
            }
        }
    } else if (MODE == 1 && vhalf) {
        // pvT[bh][d][r]; bb constant per wave, r = mi*16+quad*4+i
        const int bb = (m0 - 4096 + wm) >> 6;
        #pragma unroll
        for (int mi = 0; mi < 4; ++mi) {
            const float4 es4 = *(const float4*)&esum[mi * 16 + quad * 4];
            const float esv[4] = {es4.x, es4.y, es4.z, es4.w};
            #pragma unroll
            for (int ni = 0; ni < 4; ++ni) {
                const int n = n0 + wn + ni * 16 + fr;
                const int h = n >> 6, d = n & 63;
                #pragma unroll
                for (int i = 0; i < 4; ++i) {
                    const int r = mi * 16 + quad * 4 + i;
                    pvT[((size_t)(bb * H_ + h)) * 4096 + d * 64 + r] =
                        (_Float16)(acc[mi][ni][i] + esv[i] * bval[ni]);
                }
            }
        }
    } else {
        // Q (MODE 0) or pk (MODE 1 low half): two-pass wave-private LDS
        // transpose (32 rows per pass) + half8 coalesced row stores.
        _Float16* ct = &sm[w * 2176];   // 32 x 68
        #pragma unroll
        for (int half = 0; half < 2; ++half) {
            #pragma unroll
            for (int mi2 = 0; mi2 < 2; ++mi2) {
                const int mi = half * 2 + mi2;
                float esv[4] = {1.f, 1.f, 1.f, 1.f};
                if (MODE == 1) {
                    const float4 es4 = *(const float4*)&esum[mi * 16 + quad * 4];
                    esv[0] = es4.x; esv[1] = es4.y; esv[2] = es4.z; esv[3] = es4.w;
                }
                #pragma unroll
                for (int ni = 0; ni < 4; ++ni)
                    #pragma unroll
                    for (int i = 0; i < 4; ++i)
                        ct[(mi2 * 16 + quad * 4 + i) * 68 + ni * 16 + fr] =
                            (_Float16)(acc[mi][ni][i] + esv[i] * bval[ni]);
            }
            // wave-private: LDS ops from one wave complete in order, no barrier
            #pragma unroll
            for (int pass = 0; pass < 4; ++pass) {
                const int rr = pass * 8 + (lane >> 3);
                const int cc = (lane & 7) * 8;
                const half8_t v = *(const half8_t*)&ct[rr * 68 + cc];
                *(half8_t*)&O16a[(size_t)(m0 + wm + half * 32 + rr) * D_ + n0 + wn + cc] = v;
            }
        }
    }
}

// ---------------------------------------------------------------------------
// MFMA attention: one block per (b,h), barrier-free. pk rows strided 768 in
// pk16 (GEMM output layout); pvT compact [bh][d][r]. P round-trips a
// wave-private LDS band.
// ---------------------------------------------------------------------------
__global__ __launch_bounds__(256) void attn_kernel(
    const _Float16* __restrict__ Qh, const _Float16* __restrict__ pk16,
    const _Float16* __restrict__ pvT, _Float16* __restrict__ CTXh)
{
    __shared__ _Float16 P[64 * 80];
    const int bh = blockIdx.x, b = bh / H_, h = bh % H_;
    const int tid = threadIdx.x, w = tid >> 6, lane = tid & 63;
    const int l15 = lane & 15, quad = lane >> 4;
    const _Float16* pkB = pk16 + (size_t)(b * 64) * D_ + h * 64;
    const _Float16* pvB = pvT + (size_t)bh * 4096;
    const size_t qbase = (size_t)(b * S_) * D_ + h * HD_;

    half8_t bkf[4][2], bvf[4][2];
    #pragma unroll
    for (int ni = 0; ni < 4; ++ni)
        #pragma unroll
        for (int kk = 0; kk < 2; ++kk) {
            bkf[ni][kk] = *(const half8_t*)&pkB[(size_t)(ni * 16 + l15) * D_ + kk * 32 + quad * 8];
            bvf[ni][kk] = *(const half8_t*)&pvB[(ni * 16 + l15) * 64 + kk * 32 + quad * 8];
        }

    for (int t = w; t < 13; t += 4) {
        const int srow = t * 16;
        floatx4 acc[4] = {};
        #pragma unroll
        for (int kk = 0; kk < 2; ++kk) {
            const half8_t aq = *(const half8_t*)
                &Qh[qbase + (size_t)(srow + l15) * D_ + kk * 32 + quad * 8];
            #pragma unroll
            for (int ni = 0; ni < 4; ++ni)
                acc[ni] = __builtin_amdgcn_mfma_f32_16x16x32_f16(
                    aq, bkf[ni][kk], acc[ni], 0, 0, 0);
        }
        float p[4][4];
        #pragma unroll
        for (int i = 0; i < 4; ++i) {
            const float s0 = acc[0][i] * 0.125f, s1 = acc[1][i] * 0.125f;
            const float s2 = acc[2][i] * 0.125f, s3 = acc[3][i] * 0.125f;
            float mx = fmaxf(fmaxf(s0, s1), fmaxf(s2, s3));
            #pragma unroll
            for (int off = 1; off < 16; off <<= 1)
                mx = fmaxf(mx, __shfl_xor(mx, off, 64));
            const float e0 = __expf(s0 - mx), e1 = __expf(s1 - mx);
            const float e2 = __expf(s2 - mx), e3 = __expf(s3 - mx);
            float sme = e0 + e1 + e2 + e3;
            #pragma unroll
            for (int off = 1; off < 16; off <<= 1)
                sme += __shfl_xor(sme, off, 64);
            const float inv = 1.f / sme;
            p[0][i] = e0 * inv; p[1][i] = e1 * inv;
            p[2][i] = e2 * inv; p[3][i] = e3 * inv;
        }
        #pragma unroll
        for (int ni = 0; ni < 4; ++ni)
            #pragma unroll
            for (int i = 0; i < 4; ++i)
                P[(w * 16 + quad * 4 + i) * 80 + ni * 16 + l15] = (_Float16)p[ni][i];

        floatx4 accv[4] = {};
        #pragma unroll
        for (int kk = 0; kk < 2; ++kk) {
            const half8_t ap = *(const half8_t*)&P[(w * 16 + l15) * 80 + kk * 32 + quad * 8];
            #pragma unroll
            for (int ni = 0; ni < 4; ++ni)
                accv[ni] = __builtin_amdgcn_mfma_f32_16x16x32_f16(
                    ap, bvf[ni][kk], accv[ni], 0, 0, 0);
        }
        #pragma unroll
        for (int ni = 0; ni < 4; ++ni)
            #pragma unroll
            for (int i = 0; i < 4; ++i) {
                const int s = srow + quad * 4 + i;
                if (s < S_)
                    CTXh[qbase + (size_t)s * D_ + ni * 16 + l15] = (_Float16)accv[ni][i];
            }
    }
}

// ---------------------------------------------------------------------------
extern "C" void kernel_launch(void* const* d_in, const int* in_sizes, int n_in,
                              void* d_out, int out_size, void* d_ws, size_t ws_size,
                              hipStream_t stream) {
    const float* X   = (const float*)d_in[0];
    const float* Wq  = (const float*)d_in[1];
    const float* bq  = (const float*)d_in[2];
    const float* Wk  = (const float*)d_in[3];
    const float* bk  = (const float*)d_in[4];
    const float* Wv  = (const float*)d_in[5];
    const float* bv  = (const float*)d_in[6];
    const float* Wo  = (const float*)d_in[7];
    const float* bo  = (const float*)d_in[8];
    const float* E_k = (const float*)d_in[9];
    const float* E_v = (const float*)d_in[10];
    float* out = (float*)d_out;

    char* p = (char*)d_ws;
    _Float16* Xh   = (_Float16*)p; p += (size_t)MPAD * D_ * 2;   // reused as CTXh
    _Float16* Tcat = (_Float16*)p; p += (size_t)3 * WSZ * 2;     // Wk,Wv,Wq
    _Float16* To   = (_Float16*)p; p += (size_t)WSZ * 2;
    _Float16* Qh   = (_Float16*)p; p += (size_t)MPAD * D_ * 2;
    _Float16* EET  = (_Float16*)p; p += (size_t)128 * KE * 2;
    float* esumK   = (float*)p;    p += 64 * sizeof(float);
    float* esumV   = (float*)p;    p += 64 * sizeof(float);
    _Float16* Ybuf = (_Float16*)p; p += (size_t)8192 * D_ * 2;
    _Float16* pk16 = (_Float16*)p; p += (size_t)4096 * D_ * 2;
    _Float16* pvT  = (_Float16*)p;

    prep_kernel<<<11810, 256, 0, stream>>>(X, Wq, Wk, Wv, Wo, E_k, E_v,
                                           Xh, Tcat, To, EET, esumK, esumV);
    y_kernel<<<768, 256, 0, stream>>>(Xh, EET, Ybuf);
    gemm_t<1><<<384, 256, 0, stream>>>(Ybuf, Tcat, Tcat + WSZ,
                                       bk, bv, esumK, esumV,
                                       pk16, pvT, nullptr);
    gemm_t<0><<<624, 256, 0, stream>>>(Xh, Tcat + 2 * WSZ, nullptr,
                                       bq, nullptr, nullptr, nullptr,
                                       Qh, nullptr, nullptr);
    attn_kernel<<<BH_, 256, 0, stream>>>(Qh, pk16, pvT, Xh);
    gemm_t<2><<<624, 256, 0, stream>>>(Xh, To, nullptr,
                                       bo, nullptr, nullptr, nullptr,
                                       nullptr, nullptr, out);
}

// Round 8
// 218.943 us; speedup vs baseline: 1.0325x; 1.0325x over previous
//
#include <hip/hip_runtime.h>
#include <math.h>

#define B_   64
#define S_   197
#define D_   768
#define H_   12
#define HD_  64
#define M_   (B_ * S_)     // 12608
#define MPAD 12672         // 99*128
#define KE   224           // padded contraction length over s (7*32)
#define BH_  (B_ * H_)     // 768
#define WSZ  ((size_t)D_ * D_)   // 589824

typedef _Float16 half8_t __attribute__((ext_vector_type(8)));
typedef _Float16 half4_t __attribute__((ext_vector_type(4)));
typedef _Float16 half2_t __attribute__((ext_vector_type(2)));
typedef float floatx4 __attribute__((ext_vector_type(4)));

// async global->LDS DMA, 16B per lane; lptr must be wave-uniform (HW adds lane*16)
#define LDS_DMA16(gptr, lptr) \
  __builtin_amdgcn_global_load_lds((const __attribute__((address_space(1))) void*)(gptr), \
                                   (__attribute__((address_space(3))) void*)(lptr), 16, 0, 0)

// ---------------------------------------------------------------------------
// Fused prep: [0,9504) X->fp16 (zero-pad rows to MPAD); [9504,11808) weight
// transpose+convert (Wk,Wv,Wq -> Tcat, Wo -> To); [11808,11810) E_k/E_v ->
// EET rows [0,64)/[64,128) as [r][KE] fp16 (zero-padded s>=197) + esum[r].
// ---------------------------------------------------------------------------
__global__ __launch_bounds__(256) void prep_kernel(
    const float* __restrict__ X,
    const float* __restrict__ Wq, const float* __restrict__ Wk,
    const float* __restrict__ Wv, const float* __restrict__ Wo,
    const float* __restrict__ Ek, const float* __restrict__ Ev,
    _Float16* __restrict__ Xh,
    _Float16* __restrict__ Tcat, _Float16* __restrict__ To,
    _Float16* __restrict__ EET,
    float* __restrict__ esumK, float* __restrict__ esumV)
{
    __shared__ float tile[32][33];
    const int bid = blockIdx.x, tid = threadIdx.x;
    if (bid < 9504) {
        const int i4 = (bid * 256 + tid) * 4;
        float4 v = make_float4(0.f, 0.f, 0.f, 0.f);
        if (i4 < M_ * D_) v = *(const float4*)&X[i4];
        half4_t o = { (_Float16)v.x, (_Float16)v.y, (_Float16)v.z, (_Float16)v.w };
        *(half4_t*)&Xh[i4] = o;
        return;
    }
    int b2 = bid - 9504;
    if (b2 < 2304) {
        const int z = b2 / 576, rem = b2 % 576;
        const int bx = rem % 24, by = rem / 24;
        // z: 0->Wk, 1->Wv, 2->Wq (into Tcat), 3->Wo (into To)
        const float* W = (z == 0) ? Wk : (z == 1) ? Wv : (z == 2) ? Wq : Wo;
        _Float16* T = (z < 3) ? (Tcat + (size_t)z * WSZ) : To;
        const int n0 = bx * 32, k0 = by * 32;
        const int r = tid >> 3, c4 = (tid & 7) * 4;
        *(float4*)&tile[r][c4] = *(const float4*)&W[(size_t)(k0 + r) * D_ + n0 + c4];
        __syncthreads();
        half4_t o = { (_Float16)tile[c4 + 0][r], (_Float16)tile[c4 + 1][r],
                      (_Float16)tile[c4 + 2][r], (_Float16)tile[c4 + 3][r] };
        *(half4_t*)&T[(size_t)(n0 + r) * D_ + k0 + c4] = o;
        return;
    }
    b2 -= 2304;   // 0 -> Ek, 1 -> Ev
    const float* E = b2 ? Ev : Ek;
    _Float16* ET = EET + (size_t)b2 * 64 * KE;
    float* es = b2 ? esumV : esumK;
    for (int i = tid; i < 64 * KE; i += 256) {
        const int rr = i / KE, s = i % KE;
        ET[i] = (_Float16)((s < S_) ? E[s * 64 + rr] : 0.f);
    }
    if (tid < 64) {
        float acc = 0.f;
        for (int s = 0; s < S_; ++s) acc += E[s * 64 + tid];
        es[tid] = acc;
    }
}

// ---------------------------------------------------------------------------
// Y[b] = E^T @ X_b per batch: Ybuf rows [0,4096) = Y_k (b*64+r),
// rows [4096,8192) = Y_v.  One block per (b, 64-col tile).
// ---------------------------------------------------------------------------
__global__ __launch_bounds__(256) void y_kernel(
    const _Float16* __restrict__ Xh, const _Float16* __restrict__ EET,
    _Float16* __restrict__ Ybuf)
{
    __shared__ _Float16 Xs[KE * 66];
    const int bid = blockIdx.x;
    const int b = bid / 12, n0 = (bid % 12) * 64;
    const int tid = threadIdx.x, w = tid >> 6, lane = tid & 63;
    const int l15 = lane & 15, quad = lane >> 4;

    #pragma unroll
    for (int i = 0; i < 7; ++i) {
        const int s = i * 32 + (tid >> 3);
        const int d0 = (tid & 7) * 8;
        // rows b*197+s for s in [197,224) multiply EET's zero padding
        const half8_t v = *(const half8_t*)&Xh[(size_t)(b * S_ + s) * D_ + n0 + d0];
        #pragma unroll
        for (int jj = 0; jj < 4; ++jj) {
            half2_t t2 = { v[2 * jj], v[2 * jj + 1] };
            *(half2_t*)&Xs[s * 66 + d0 + 2 * jj] = t2;
        }
    }
    __syncthreads();

    floatx4 acc[2][4] = {};
    #pragma unroll
    for (int k7 = 0; k7 < 7; ++k7) {
        half8_t af[2];
        #pragma unroll
        for (int mi = 0; mi < 2; ++mi)
            af[mi] = *(const half8_t*)&EET[(w * 32 + mi * 16 + l15) * KE + k7 * 32 + quad * 8];
        #pragma unroll
        for (int ni = 0; ni < 4; ++ni) {
            const int sb = k7 * 32 + quad * 8;
            half8_t bf;
            #pragma unroll
            for (int jj = 0; jj < 8; ++jj) bf[jj] = Xs[(sb + jj) * 66 + ni * 16 + l15];
            #pragma unroll
            for (int mi = 0; mi < 2; ++mi)
                acc[mi][ni] = __builtin_amdgcn_mfma_f32_16x16x32_f16(
                    af[mi], bf, acc[mi][ni], 0, 0, 0);
        }
    }

    #pragma unroll
    for (int mi = 0; mi < 2; ++mi)
        #pragma unroll
        for (int ni = 0; ni < 4; ++ni)
            #pragma unroll
            for (int i = 0; i < 4; ++i) {
                const int m_local = w * 32 + mi * 16 + quad * 4 + i;
                const int row = (m_local >> 6) * 4096 + b * 64 + (m_local & 63);
                Ybuf[(size_t)row * D_ + n0 + ni * 16 + l15] = (_Float16)acc[mi][ni][i];
            }
}

// ===========================================================================
// Shared BK=64 GEMM core pieces (128x128 tile, 4 waves, XOR chunk swizzle).
// LDS: A stage [0,8192) halfs, B stage [8192,16384) -> 32 KB.
// Swizzle: chunk c (8 halfs) of row r lives at slot c ^ (r&7).
// ===========================================================================

// ---------------------------------------------------------------------------
// Fused Q + PKV GEMM, 1008 blocks:
//   [0,624):   Qh = Xh @ Wq^T + bq              (fp16 transpose epilogue)
//   [624,1008): m_blk<32: pk16 = Yk@Wk^T + esumK[r]*bk[n]  (fp16 rows)
//               m_blk>=32: pvT[bh][d][r] = Yv@Wv^T + esumV[r]*bv[n]
// ---------------------------------------------------------------------------
__global__ __launch_bounds__(256) void gemm_qpkv(
    const _Float16* __restrict__ Xh, const _Float16* __restrict__ Ybuf,
    const _Float16* __restrict__ Tcat,
    const float* __restrict__ bq, const float* __restrict__ bk,
    const float* __restrict__ bv,
    const float* __restrict__ esumK, const float* __restrict__ esumV,
    _Float16* __restrict__ Qh, _Float16* __restrict__ pk16,
    _Float16* __restrict__ pvT)
{
    __shared__ _Float16 sm[16384];
    const int bid = blockIdx.x;
    const _Float16 *A, *W;
    const float *bias, *esum;
    _Float16* O16;
    bool pvmode = false;
    int m0, n0;
    if (bid < 624) {                 // Q
        const int xcd = bid & 7, t = bid >> 3;
        const int slot = t / 6, j = t - slot * 6;
        const int m_blk = slot * 8 + xcd;
        if (m_blk >= MPAD / 128) return;
        m0 = m_blk * 128; n0 = j * 128;
        A = Xh; W = Tcat + 2 * WSZ + (size_t)n0 * D_;
        bias = bq; esum = nullptr; O16 = Qh;
    } else {                         // PKV
        const int b2 = bid - 624;
        const int xcd = b2 & 7, t = b2 >> 3;
        const int slot = t / 6, j = t - slot * 6;
        const int m_blk = slot * 8 + xcd;    // [0,64)
        m0 = m_blk * 128; n0 = j * 128;
        pvmode = (m_blk >= 32);
        A = Ybuf; W = Tcat + (pvmode ? WSZ : 0) + (size_t)n0 * D_;
        bias = pvmode ? bv : bk; esum = pvmode ? esumV : esumK;
        O16 = pk16;
    }

    const int tid = threadIdx.x;
    const int w = tid >> 6, lane = tid & 63;
    const int fr = lane & 15, quad = lane >> 4, f7 = lane & 7;
    const int l3 = lane >> 3;
    const int csrc = ((lane & 7) ^ l3) * 8;
    const int wm = (w >> 1) * 64, wn = (w & 1) * 64;

    const _Float16* Abase = A + (size_t)(m0 + w * 32 + l3) * D_ + csrc;
    const _Float16* Wbase = W + (size_t)(w * 32 + l3) * D_ + csrc;

    floatx4 acc[4][4] = {};

    for (int k0 = 0; k0 < D_; k0 += 64) {
        #pragma unroll
        for (int j = 0; j < 4; ++j) {
            LDS_DMA16(Abase + (size_t)(j * 8) * D_ + k0, &sm[w * 2048 + j * 512]);
            LDS_DMA16(Wbase + (size_t)(j * 8) * D_ + k0, &sm[8192 + w * 2048 + j * 512]);
        }
        __syncthreads();
        #pragma unroll
        for (int ksub = 0; ksub < 2; ++ksub) {
            const int sa = ((ksub * 4 + quad) ^ f7) * 8;
            half8_t af[4], bf[4];
            #pragma unroll
            for (int i = 0; i < 4; ++i) {
                af[i] = *(const half8_t*)&sm[(wm + i * 16 + fr) * 64 + sa];
                bf[i] = *(const half8_t*)&sm[8192 + (wn + i * 16 + fr) * 64 + sa];
            }
            #pragma unroll
            for (int mi = 0; mi < 4; ++mi)
                #pragma unroll
                for (int ni = 0; ni < 4; ++ni)
                    acc[mi][ni] = __builtin_amdgcn_mfma_f32_16x16x32_f16(
                        af[mi], bf[ni], acc[mi][ni], 0, 0, 0);
        }
        __syncthreads();
    }

    float bval[4];
    #pragma unroll
    for (int ni = 0; ni < 4; ++ni)
        bval[ni] = bias[n0 + wn + ni * 16 + fr];

    if (pvmode) {
        // pvT[bh][d][r]; bb constant per wave, r = mi*16+quad*4+i
        const int bb = (m0 - 4096 + wm) >> 6;
        #pragma unroll
        for (int mi = 0; mi < 4; ++mi) {
            const float4 es4 = *(const float4*)&esum[mi * 16 + quad * 4];
            const float esv[4] = {es4.x, es4.y, es4.z, es4.w};
            #pragma unroll
            for (int ni = 0; ni < 4; ++ni) {
                const int n = n0 + wn + ni * 16 + fr;
                const int h = n >> 6, d = n & 63;
                #pragma unroll
                for (int i = 0; i < 4; ++i) {
                    const int r = mi * 16 + quad * 4 + i;
                    pvT[((size_t)(bb * H_ + h)) * 4096 + d * 64 + r] =
                        (_Float16)(acc[mi][ni][i] + esv[i] * bval[ni]);
                }
            }
        }
    } else {
        // Q / pk: two-pass wave-private LDS transpose + half8 row stores
        _Float16* ct = &sm[w * 2176];   // 32 x 68
        #pragma unroll
        for (int half = 0; half < 2; ++half) {
            #pragma unroll
            for (int mi2 = 0; mi2 < 2; ++mi2) {
                const int mi = half * 2 + mi2;
                float esv[4] = {1.f, 1.f, 1.f, 1.f};
                if (esum) {
                    const float4 es4 = *(const float4*)&esum[mi * 16 + quad * 4];
                    esv[0] = es4.x; esv[1] = es4.y; esv[2] = es4.z; esv[3] = es4.w;
                }
                #pragma unroll
                for (int ni = 0; ni < 4; ++ni)
                    #pragma unroll
                    for (int i = 0; i < 4; ++i)
                        ct[(mi2 * 16 + quad * 4 + i) * 68 + ni * 16 + fr] =
                            (_Float16)(acc[mi][ni][i] + esv[i] * bval[ni]);
            }
            #pragma unroll
            for (int pass = 0; pass < 4; ++pass) {
                const int rr = pass * 8 + (lane >> 3);
                const int cc = (lane & 7) * 8;
                const half8_t v = *(const half8_t*)&ct[rr * 68 + cc];
                *(half8_t*)&O16[(size_t)(m0 + wm + half * 32 + rr) * D_ + n0 + wn + cc] = v;
            }
        }
    }
}

// ---------------------------------------------------------------------------
// O-projection GEMM, 624 blocks: out = CTX @ Wo^T + bo (fp32, guard M_).
// ---------------------------------------------------------------------------
__global__ __launch_bounds__(256) void gemm_o(
    const _Float16* __restrict__ CTX, const _Float16* __restrict__ To,
    const float* __restrict__ bo, float* __restrict__ O32)
{
    __shared__ _Float16 sm[16384];
    const int xcd = blockIdx.x & 7, t = blockIdx.x >> 3;
    const int slot = t / 6, j = t - slot * 6;
    const int m_blk = slot * 8 + xcd;
    if (m_blk >= MPAD / 128) return;
    const int m0 = m_blk * 128, n0 = j * 128;

    const int tid = threadIdx.x;
    const int w = tid >> 6, lane = tid & 63;
    const int fr = lane & 15, quad = lane >> 4, f7 = lane & 7;
    const int l3 = lane >> 3;
    const int csrc = ((lane & 7) ^ l3) * 8;
    const int wm = (w >> 1) * 64, wn = (w & 1) * 64;

    const _Float16* Abase = CTX + (size_t)(m0 + w * 32 + l3) * D_ + csrc;
    const _Float16* Wbase = To + (size_t)(n0 + w * 32 + l3) * D_ + csrc;

    floatx4 acc[4][4] = {};

    for (int k0 = 0; k0 < D_; k0 += 64) {
        #pragma unroll
        for (int j2 = 0; j2 < 4; ++j2) {
            LDS_DMA16(Abase + (size_t)(j2 * 8) * D_ + k0, &sm[w * 2048 + j2 * 512]);
            LDS_DMA16(Wbase + (size_t)(j2 * 8) * D_ + k0, &sm[8192 + w * 2048 + j2 * 512]);
        }
        __syncthreads();
        #pragma unroll
        for (int ksub = 0; ksub < 2; ++ksub) {
            const int sa = ((ksub * 4 + quad) ^ f7) * 8;
            half8_t af[4], bf[4];
            #pragma unroll
            for (int i = 0; i < 4; ++i) {
                af[i] = *(const half8_t*)&sm[(wm + i * 16 + fr) * 64 + sa];
                bf[i] = *(const half8_t*)&sm[8192 + (wn + i * 16 + fr) * 64 + sa];
            }
            #pragma unroll
            for (int mi = 0; mi < 4; ++mi)
                #pragma unroll
                for (int ni = 0; ni < 4; ++ni)
                    acc[mi][ni] = __builtin_amdgcn_mfma_f32_16x16x32_f16(
                        af[mi], bf[ni], acc[mi][ni], 0, 0, 0);
        }
        __syncthreads();
    }

    float bval[4];
    #pragma unroll
    for (int ni = 0; ni < 4; ++ni)
        bval[ni] = bo[n0 + wn + ni * 16 + fr];

    const int rq = quad * 4;
    if (m0 + 128 <= M_) {
        #pragma unroll
        for (int ni = 0; ni < 4; ++ni) {
            const int n = n0 + wn + ni * 16 + fr;
            #pragma unroll
            for (int mi = 0; mi < 4; ++mi)
                #pragma unroll
                for (int i = 0; i < 4; ++i)
                    O32[(size_t)(m0 + wm + mi * 16 + rq + i) * D_ + n] =
                        acc[mi][ni][i] + bval[ni];
        }
    } else {
        #pragma unroll
        for (int ni = 0; ni < 4; ++ni) {
            const int n = n0 + wn + ni * 16 + fr;
            #pragma unroll
            for (int mi = 0; mi < 4; ++mi)
                #pragma unroll
                for (int i = 0; i < 4; ++i) {
                    const int m = m0 + wm + mi * 16 + rq + i;
                    if (m < M_)
                        O32[(size_t)m * D_ + n] = acc[mi][ni][i] + bval[ni];
                }
        }
    }
}

// ---------------------------------------------------------------------------
// MFMA attention: one block per (b,h), barrier-free. pk rows strided 768 in
// pk16 (GEMM output layout); pvT compact [bh][d][r]. P round-trips a
// wave-private LDS band.
// ---------------------------------------------------------------------------
__global__ __launch_bounds__(256) void attn_kernel(
    const _Float16* __restrict__ Qh, const _Float16* __restrict__ pk16,
    const _Float16* __restrict__ pvT, _Float16* __restrict__ CTXh)
{
    __shared__ _Float16 P[64 * 80];
    const int bh = blockIdx.x, b = bh / H_, h = bh % H_;
    const int tid = threadIdx.x, w = tid >> 6, lane = tid & 63;
    const int l15 = lane & 15, quad = lane >> 4;
    const _Float16* pkB = pk16 + (size_t)(b * 64) * D_ + h * 64;
    const _Float16* pvB = pvT + (size_t)bh * 4096;
    const size_t qbase = (size_t)(b * S_) * D_ + h * HD_;

    half8_t bkf[4][2], bvf[4][2];
    #pragma unroll
    for (int ni = 0; ni < 4; ++ni)
        #pragma unroll
        for (int kk = 0; kk < 2; ++kk) {
            bkf[ni][kk] = *(const half8_t*)&pkB[(size_t)(ni * 16 + l15) * D_ + kk * 32 + quad * 8];
            bvf[ni][kk] = *(const half8_t*)&pvB[(ni * 16 + l15) * 64 + kk * 32 + quad * 8];
        }

    for (int t = w; t < 13; t += 4) {
        const int srow = t * 16;
        floatx4 acc[4] = {};
        #pragma unroll
        for (int kk = 0; kk < 2; ++kk) {
            const half8_t aq = *(const half8_t*)
                &Qh[qbase + (size_t)(srow + l15) * D_ + kk * 32 + quad * 8];
            #pragma unroll
            for (int ni = 0; ni < 4; ++ni)
                acc[ni] = __builtin_amdgcn_mfma_f32_16x16x32_f16(
                    aq, bkf[ni][kk], acc[ni], 0, 0, 0);
        }
        float p[4][4];
        #pragma unroll
        for (int i = 0; i < 4; ++i) {
            const float s0 = acc[0][i] * 0.125f, s1 = acc[1][i] * 0.125f;
            const float s2 = acc[2][i] * 0.125f, s3 = acc[3][i] * 0.125f;
            float mx = fmaxf(fmaxf(s0, s1), fmaxf(s2, s3));
            #pragma unroll
            for (int off = 1; off < 16; off <<= 1)
                mx = fmaxf(mx, __shfl_xor(mx, off, 64));
            const float e0 = __expf(s0 - mx), e1 = __expf(s1 - mx);
            const float e2 = __expf(s2 - mx), e3 = __expf(s3 - mx);
            float sme = e0 + e1 + e2 + e3;
            #pragma unroll
            for (int off = 1; off < 16; off <<= 1)
                sme += __shfl_xor(sme, off, 64);
            const float inv = 1.f / sme;
            p[0][i] = e0 * inv; p[1][i] = e1 * inv;
            p[2][i] = e2 * inv; p[3][i] = e3 * inv;
        }
        #pragma unroll
        for (int ni = 0; ni < 4; ++ni)
            #pragma unroll
            for (int i = 0; i < 4; ++i)
                P[(w * 16 + quad * 4 + i) * 80 + ni * 16 + l15] = (_Float16)p[ni][i];

        floatx4 accv[4] = {};
        #pragma unroll
        for (int kk = 0; kk < 2; ++kk) {
            const half8_t ap = *(const half8_t*)&P[(w * 16 + l15) * 80 + kk * 32 + quad * 8];
            #pragma unroll
            for (int ni = 0; ni < 4; ++ni)
                accv[ni] = __builtin_amdgcn_mfma_f32_16x16x32_f16(
                    ap, bvf[ni][kk], accv[ni], 0, 0, 0);
        }
        #pragma unroll
        for (int ni = 0; ni < 4; ++ni)
            #pragma unroll
            for (int i = 0; i < 4; ++i) {
                const int s = srow + quad * 4 + i;
                if (s < S_)
                    CTXh[qbase + (size_t)s * D_ + ni * 16 + l15] = (_Float16)accv[ni][i];
            }
    }
}

// ---------------------------------------------------------------------------
extern "C" void kernel_launch(void* const* d_in, const int* in_sizes, int n_in,
                              void* d_out, int out_size, void* d_ws, size_t ws_size,
                              hipStream_t stream) {
    const float* X   = (const float*)d_in[0];
    const float* Wq  = (const float*)d_in[1];
    const float* bq  = (const float*)d_in[2];
    const float* Wk  = (const float*)d_in[3];
    const float* bk  = (const float*)d_in[4];
    const float* Wv  = (const float*)d_in[5];
    const float* bv  = (const float*)d_in[6];
    const float* Wo  = (const float*)d_in[7];
    const float* bo  = (const float*)d_in[8];
    const float* E_k = (const float*)d_in[9];
    const float* E_v = (const float*)d_in[10];
    float* out = (float*)d_out;

    char* p = (char*)d_ws;
    _Float16* Xh   = (_Float16*)p; p += (size_t)MPAD * D_ * 2;   // reused as CTXh
    _Float16* Tcat = (_Float16*)p; p += (size_t)3 * WSZ * 2;     // Wk,Wv,Wq
    _Float16* To   = (_Float16*)p; p += (size_t)WSZ * 2;
    _Float16* Qh   = (_Float16*)p; p += (size_t)MPAD * D_ * 2;
    _Float16* EET  = (_Float16*)p; p += (size_t)128 * KE * 2;
    float* esumK   = (float*)p;    p += 64 * sizeof(float);
    float* esumV   = (float*)p;    p += 64 * sizeof(float);
    _Float16* Ybuf = (_Float16*)p; p += (size_t)8192 * D_ * 2;
    _Float16* pk16 = (_Float16*)p; p += (size_t)4096 * D_ * 2;
    _Float16* pvT  = (_Float16*)p;

    prep_kernel<<<11810, 256, 0, stream>>>(X, Wq, Wk, Wv, Wo, E_k, E_v,
                                           Xh, Tcat, To, EET, esumK, esumV);
    y_kernel<<<768, 256, 0, stream>>>(Xh, EET, Ybuf);
    gemm_qpkv<<<1008, 256, 0, stream>>>(Xh, Ybuf, Tcat,
                                        bq, bk, bv, esumK, esumV,
                                        Qh, pk16, pvT);
    attn_kernel<<<BH_, 256, 0, stream>>>(Qh, pk16, pvT, Xh);
    gemm_o<<<624, 256, 0, stream>>>(Xh, To, bo, out);
}

// Round 9
// 210.784 us; speedup vs baseline: 1.0725x; 1.0387x over previous
//
#include <hip/hip_runtime.h>
#include <math.h>

#define B_   64
#define S_   197
#define D_   768
#define H_   12
#define HD_  64
#define M_   (B_ * S_)     // 12608
#define MPAD 12672         // 99*128
#define KE   224           // padded contraction length over s (7*32)
#define BH_  (B_ * H_)     // 768
#define WSZ  ((size_t)D_ * D_)   // 589824

typedef _Float16 half8_t __attribute__((ext_vector_type(8)));
typedef _Float16 half4_t __attribute__((ext_vector_type(4)));
typedef _Float16 half2_t __attribute__((ext_vector_type(2)));
typedef float floatx4 __attribute__((ext_vector_type(4)));

// async global->LDS DMA, 16B per lane; lptr must be wave-uniform (HW adds lane*16)
#define LDS_DMA16(gptr, lptr) \
  __builtin_amdgcn_global_load_lds((const __attribute__((address_space(1))) void*)(gptr), \
                                   (__attribute__((address_space(3))) void*)(lptr), 16, 0, 0)

// ---------------------------------------------------------------------------
// Fused prep: [0,9504) X->fp16 (zero-pad rows to MPAD); [9504,11808) weight
// transpose+convert (Wk,Wv,Wq -> Tcat, Wo -> To); [11808,11810) E_k/E_v ->
// EET rows [0,64)/[64,128) as [r][KE] fp16 (zero-padded s>=197) + esum[r].
// ---------------------------------------------------------------------------
__global__ __launch_bounds__(256) void prep_kernel(
    const float* __restrict__ X,
    const float* __restrict__ Wq, const float* __restrict__ Wk,
    const float* __restrict__ Wv, const float* __restrict__ Wo,
    const float* __restrict__ Ek, const float* __restrict__ Ev,
    _Float16* __restrict__ Xh,
    _Float16* __restrict__ Tcat, _Float16* __restrict__ To,
    _Float16* __restrict__ EET,
    float* __restrict__ esumK, float* __restrict__ esumV)
{
    __shared__ float tile[32][33];
    const int bid = blockIdx.x, tid = threadIdx.x;
    if (bid < 9504) {
        const int i4 = (bid * 256 + tid) * 4;
        float4 v = make_float4(0.f, 0.f, 0.f, 0.f);
        if (i4 < M_ * D_) v = *(const float4*)&X[i4];
        half4_t o = { (_Float16)v.x, (_Float16)v.y, (_Float16)v.z, (_Float16)v.w };
        *(half4_t*)&Xh[i4] = o;
        return;
    }
    int b2 = bid - 9504;
    if (b2 < 2304) {
        const int z = b2 / 576, rem = b2 % 576;
        const int bx = rem % 24, by = rem / 24;
        // z: 0->Wk, 1->Wv, 2->Wq (into Tcat), 3->Wo (into To)
        const float* W = (z == 0) ? Wk : (z == 1) ? Wv : (z == 2) ? Wq : Wo;
        _Float16* T = (z < 3) ? (Tcat + (size_t)z * WSZ) : To;
        const int n0 = bx * 32, k0 = by * 32;
        const int r = tid >> 3, c4 = (tid & 7) * 4;
        *(float4*)&tile[r][c4] = *(const float4*)&W[(size_t)(k0 + r) * D_ + n0 + c4];
        __syncthreads();
        half4_t o = { (_Float16)tile[c4 + 0][r], (_Float16)tile[c4 + 1][r],
                      (_Float16)tile[c4 + 2][r], (_Float16)tile[c4 + 3][r] };
        *(half4_t*)&T[(size_t)(n0 + r) * D_ + k0 + c4] = o;
        return;
    }
    b2 -= 2304;   // 0 -> Ek, 1 -> Ev
    const float* E = b2 ? Ev : Ek;
    _Float16* ET = EET + (size_t)b2 * 64 * KE;
    float* es = b2 ? esumV : esumK;
    for (int i = tid; i < 64 * KE; i += 256) {
        const int rr = i / KE, s = i % KE;
        ET[i] = (_Float16)((s < S_) ? E[s * 64 + rr] : 0.f);
    }
    if (tid < 64) {
        float acc = 0.f;
        for (int s = 0; s < S_; ++s) acc += E[s * 64 + tid];
        es[tid] = acc;
    }
}

// ---------------------------------------------------------------------------
// Y[b] = E^T @ X_b per batch: Ybuf rows [0,4096) = Y_k (b*64+r),
// rows [4096,8192) = Y_v.  One block per (b, 64-col tile).
// ---------------------------------------------------------------------------
__global__ __launch_bounds__(256) void y_kernel(
    const _Float16* __restrict__ Xh, const _Float16* __restrict__ EET,
    _Float16* __restrict__ Ybuf)
{
    __shared__ _Float16 Xs[KE * 66];
    const int bid = blockIdx.x;
    const int b = bid / 12, n0 = (bid % 12) * 64;
    const int tid = threadIdx.x, w = tid >> 6, lane = tid & 63;
    const int l15 = lane & 15, quad = lane >> 4;

    #pragma unroll
    for (int i = 0; i < 7; ++i) {
        const int s = i * 32 + (tid >> 3);
        const int d0 = (tid & 7) * 8;
        // rows b*197+s for s in [197,224) multiply EET's zero padding
        const half8_t v = *(const half8_t*)&Xh[(size_t)(b * S_ + s) * D_ + n0 + d0];
        #pragma unroll
        for (int jj = 0; jj < 4; ++jj) {
            half2_t t2 = { v[2 * jj], v[2 * jj + 1] };
            *(half2_t*)&Xs[s * 66 + d0 + 2 * jj] = t2;
        }
    }
    __syncthreads();

    floatx4 acc[2][4] = {};
    #pragma unroll
    for (int k7 = 0; k7 < 7; ++k7) {
        half8_t af[2];
        #pragma unroll
        for (int mi = 0; mi < 2; ++mi)
            af[mi] = *(const half8_t*)&EET[(w * 32 + mi * 16 + l15) * KE + k7 * 32 + quad * 8];
        #pragma unroll
        for (int ni = 0; ni < 4; ++ni) {
            const int sb = k7 * 32 + quad * 8;
            half8_t bf;
            #pragma unroll
            for (int jj = 0; jj < 8; ++jj) bf[jj] = Xs[(sb + jj) * 66 + ni * 16 + l15];
            #pragma unroll
            for (int mi = 0; mi < 2; ++mi)
                acc[mi][ni] = __builtin_amdgcn_mfma_f32_16x16x32_f16(
                    af[mi], bf, acc[mi][ni], 0, 0, 0);
        }
    }

    #pragma unroll
    for (int mi = 0; mi < 2; ++mi)
        #pragma unroll
        for (int ni = 0; ni < 4; ++ni)
            #pragma unroll
            for (int i = 0; i < 4; ++i) {
                const int m_local = w * 32 + mi * 16 + quad * 4 + i;
                const int row = (m_local >> 6) * 4096 + b * 64 + (m_local & 63);
                Ybuf[(size_t)row * D_ + n0 + ni * 16 + l15] = (_Float16)acc[mi][ni][i];
            }
}

// ---------------------------------------------------------------------------
// Fused Q + PKV GEMM, 1008 blocks, 128x128 tile, BK=64, XOR chunk swizzle.
// Single epilogue path for all modes (wave-private ct transpose, row-major
// fp16 output): [0,624) Qh = Xh@Wq^T+bq; [624,1008): m_blk<32:
// pk16[b*64+r][h*64+d] = Yk@Wk^T + esumK[r]*bk[n]; m_blk>=32: pv16 same for V.
// ---------------------------------------------------------------------------
__global__ __launch_bounds__(256) void gemm_qpkv(
    const _Float16* __restrict__ Xh, const _Float16* __restrict__ Ybuf,
    const _Float16* __restrict__ Tcat,
    const float* __restrict__ bq, const float* __restrict__ bk,
    const float* __restrict__ bv,
    const float* __restrict__ esumK, const float* __restrict__ esumV,
    _Float16* __restrict__ Qh, _Float16* __restrict__ pk16,
    _Float16* __restrict__ pv16)
{
    __shared__ _Float16 sm[16384];
    const int bid = blockIdx.x;
    const _Float16 *A, *W;
    const float *bias, *esum;
    _Float16* O16;
    int m0, n0, rowb;
    if (bid < 624) {                 // Q
        const int xcd = bid & 7, t = bid >> 3;
        const int slot = t / 6, j = t - slot * 6;
        const int m_blk = slot * 8 + xcd;
        if (m_blk >= MPAD / 128) return;
        m0 = m_blk * 128; n0 = j * 128; rowb = m0;
        A = Xh; W = Tcat + 2 * WSZ + (size_t)n0 * D_;
        bias = bq; esum = nullptr; O16 = Qh;
    } else {                         // PKV
        const int b2 = bid - 624;
        const int xcd = b2 & 7, t = b2 >> 3;
        const int slot = t / 6, j = t - slot * 6;
        const int m_blk = slot * 8 + xcd;    // [0,64)
        m0 = m_blk * 128; n0 = j * 128;
        const bool pv = (m_blk >= 32);
        rowb = pv ? m0 - 4096 : m0;
        A = Ybuf; W = Tcat + (pv ? WSZ : 0) + (size_t)n0 * D_;
        bias = pv ? bv : bk; esum = pv ? esumV : esumK;
        O16 = pv ? pv16 : pk16;
    }

    const int tid = threadIdx.x;
    const int w = tid >> 6, lane = tid & 63;
    const int fr = lane & 15, quad = lane >> 4, f7 = lane & 7;
    const int l3 = lane >> 3;
    const int csrc = ((lane & 7) ^ l3) * 8;
    const int wm = (w >> 1) * 64, wn = (w & 1) * 64;

    const _Float16* Abase = A + (size_t)(m0 + w * 32 + l3) * D_ + csrc;
    const _Float16* Wbase = W + (size_t)(w * 32 + l3) * D_ + csrc;

    floatx4 acc[4][4] = {};

    for (int k0 = 0; k0 < D_; k0 += 64) {
        #pragma unroll
        for (int j = 0; j < 4; ++j) {
            LDS_DMA16(Abase + (size_t)(j * 8) * D_ + k0, &sm[w * 2048 + j * 512]);
            LDS_DMA16(Wbase + (size_t)(j * 8) * D_ + k0, &sm[8192 + w * 2048 + j * 512]);
        }
        __syncthreads();
        #pragma unroll
        for (int ksub = 0; ksub < 2; ++ksub) {
            const int sa = ((ksub * 4 + quad) ^ f7) * 8;
            half8_t af[4], bf[4];
            #pragma unroll
            for (int i = 0; i < 4; ++i) {
                af[i] = *(const half8_t*)&sm[(wm + i * 16 + fr) * 64 + sa];
                bf[i] = *(const half8_t*)&sm[8192 + (wn + i * 16 + fr) * 64 + sa];
            }
            #pragma unroll
            for (int mi = 0; mi < 4; ++mi)
                #pragma unroll
                for (int ni = 0; ni < 4; ++ni)
                    acc[mi][ni] = __builtin_amdgcn_mfma_f32_16x16x32_f16(
                        af[mi], bf[ni], acc[mi][ni], 0, 0, 0);
        }
        __syncthreads();
    }

    float bval[4];
    #pragma unroll
    for (int ni = 0; ni < 4; ++ni)
        bval[ni] = bias[n0 + wn + ni * 16 + fr];

    // single epilogue: two-pass wave-private LDS transpose + half8 row stores
    _Float16* ct = &sm[w * 2176];   // 32 x 68
    #pragma unroll
    for (int half = 0; half < 2; ++half) {
        #pragma unroll
        for (int mi2 = 0; mi2 < 2; ++mi2) {
            const int mi = half * 2 + mi2;
            float esv[4] = {1.f, 1.f, 1.f, 1.f};
            if (esum) {
                const float4 es4 = *(const float4*)&esum[mi * 16 + quad * 4];
                esv[0] = es4.x; esv[1] = es4.y; esv[2] = es4.z; esv[3] = es4.w;
            }
            #pragma unroll
            for (int ni = 0; ni < 4; ++ni)
                #pragma unroll
                for (int i = 0; i < 4; ++i)
                    ct[(mi2 * 16 + quad * 4 + i) * 68 + ni * 16 + fr] =
                        (_Float16)(acc[mi][ni][i] + esv[i] * bval[ni]);
        }
        #pragma unroll
        for (int pass = 0; pass < 4; ++pass) {
            const int rr = pass * 8 + (lane >> 3);
            const int cc = (lane & 7) * 8;
            const half8_t v = *(const half8_t*)&ct[rr * 68 + cc];
            *(half8_t*)&O16[(size_t)(rowb + wm + half * 32 + rr) * D_ + n0 + wn + cc] = v;
        }
    }
}

// ---------------------------------------------------------------------------
// O-projection GEMM, 64x128 tile, BK=64, 1200 blocks (occupancy supply):
// out = CTX @ Wo^T + bo (fp32, guard M_).  Wave (wr,wc) owns 32x64.
// LDS: A [0,4096) halfs (64x64), B [4096,12288) (128x64) = 24.5 KB.
// ---------------------------------------------------------------------------
__global__ __launch_bounds__(256) void gemm_o(
    const _Float16* __restrict__ CTX, const _Float16* __restrict__ To,
    const float* __restrict__ bo, float* __restrict__ O32)
{
    __shared__ _Float16 sm[12288];
    const int xcd = blockIdx.x & 7, t = blockIdx.x >> 3;
    const int slot = t / 6, j = t - slot * 6;
    const int m_blk = slot * 8 + xcd;
    if (m_blk >= MPAD / 64) return;
    const int m0 = m_blk * 64, n0 = j * 128;

    const int tid = threadIdx.x;
    const int w = tid >> 6, lane = tid & 63;
    const int fr = lane & 15, quad = lane >> 4, f7 = lane & 7;
    const int l3 = lane >> 3;
    const int csrc = ((lane & 7) ^ l3) * 8;
    const int wm = (w >> 1) * 32, wn = (w & 1) * 64;

    const _Float16* Abase = CTX + (size_t)(m0 + w * 16 + l3) * D_ + csrc;
    const _Float16* Wbase = To + (size_t)(n0 + w * 32 + l3) * D_ + csrc;

    floatx4 acc[2][4] = {};

    for (int k0 = 0; k0 < D_; k0 += 64) {
        #pragma unroll
        for (int j2 = 0; j2 < 2; ++j2)
            LDS_DMA16(Abase + (size_t)(j2 * 8) * D_ + k0, &sm[w * 1024 + j2 * 512]);
        #pragma unroll
        for (int j2 = 0; j2 < 4; ++j2)
            LDS_DMA16(Wbase + (size_t)(j2 * 8) * D_ + k0, &sm[4096 + w * 2048 + j2 * 512]);
        __syncthreads();
        #pragma unroll
        for (int ksub = 0; ksub < 2; ++ksub) {
            const int sa = ((ksub * 4 + quad) ^ f7) * 8;
            half8_t af[2], bf[4];
            #pragma unroll
            for (int i = 0; i < 2; ++i)
                af[i] = *(const half8_t*)&sm[(wm + i * 16 + fr) * 64 + sa];
            #pragma unroll
            for (int i = 0; i < 4; ++i)
                bf[i] = *(const half8_t*)&sm[4096 + (wn + i * 16 + fr) * 64 + sa];
            #pragma unroll
            for (int mi = 0; mi < 2; ++mi)
                #pragma unroll
                for (int ni = 0; ni < 4; ++ni)
                    acc[mi][ni] = __builtin_amdgcn_mfma_f32_16x16x32_f16(
                        af[mi], bf[ni], acc[mi][ni], 0, 0, 0);
        }
        __syncthreads();
    }

    float bval[4];
    #pragma unroll
    for (int ni = 0; ni < 4; ++ni)
        bval[ni] = bo[n0 + wn + ni * 16 + fr];

    const int rq = quad * 4;
    if (m0 + 64 <= M_) {
        #pragma unroll
        for (int ni = 0; ni < 4; ++ni) {
            const int n = n0 + wn + ni * 16 + fr;
            #pragma unroll
            for (int mi = 0; mi < 2; ++mi)
                #pragma unroll
                for (int i = 0; i < 4; ++i)
                    O32[(size_t)(m0 + wm + mi * 16 + rq + i) * D_ + n] =
                        acc[mi][ni][i] + bval[ni];
        }
    } else {
        #pragma unroll
        for (int ni = 0; ni < 4; ++ni) {
            const int n = n0 + wn + ni * 16 + fr;
            #pragma unroll
            for (int mi = 0; mi < 2; ++mi)
                #pragma unroll
                for (int i = 0; i < 4; ++i) {
                    const int m = m0 + wm + mi * 16 + rq + i;
                    if (m < M_)
                        O32[(size_t)m * D_ + n] = acc[mi][ni][i] + bval[ni];
                }
        }
    }
}

// ---------------------------------------------------------------------------
// MFMA attention: one block per (b,h), barrier-free. pk/pv rows strided 768
// (GEMM row-major outputs); pv B-frags built from one-time scalar gathers.
// P round-trips a wave-private LDS band.
// ---------------------------------------------------------------------------
__global__ __launch_bounds__(256) void attn_kernel(
    const _Float16* __restrict__ Qh, const _Float16* __restrict__ pk16,
    const _Float16* __restrict__ pv16, _Float16* __restrict__ CTXh)
{
    __shared__ _Float16 P[64 * 80];
    const int bh = blockIdx.x, b = bh / H_, h = bh % H_;
    const int tid = threadIdx.x, w = tid >> 6, lane = tid & 63;
    const int l15 = lane & 15, quad = lane >> 4;
    const _Float16* pkB = pk16 + (size_t)(b * 64) * D_ + h * 64;
    const _Float16* pvB = pv16 + (size_t)(b * 64) * D_ + h * 64;
    const size_t qbase = (size_t)(b * S_) * D_ + h * HD_;

    half8_t bkf[4][2], bvf[4][2];
    #pragma unroll
    for (int ni = 0; ni < 4; ++ni)
        #pragma unroll
        for (int kk = 0; kk < 2; ++kk) {
            bkf[ni][kk] = *(const half8_t*)&pkB[(size_t)(ni * 16 + l15) * D_ + kk * 32 + quad * 8];
            #pragma unroll
            for (int jj = 0; jj < 8; ++jj)
                bvf[ni][kk][jj] = pvB[(size_t)(kk * 32 + quad * 8 + jj) * D_ + ni * 16 + l15];
        }

    for (int t = w; t < 13; t += 4) {
        const int srow = t * 16;
        floatx4 acc[4] = {};
        #pragma unroll
        for (int kk = 0; kk < 2; ++kk) {
            const half8_t aq = *(const half8_t*)
                &Qh[qbase + (size_t)(srow + l15) * D_ + kk * 32 + quad * 8];
            #pragma unroll
            for (int ni = 0; ni < 4; ++ni)
                acc[ni] = __builtin_amdgcn_mfma_f32_16x16x32_f16(
                    aq, bkf[ni][kk], acc[ni], 0, 0, 0);
        }
        float p[4][4];
        #pragma unroll
        for (int i = 0; i < 4; ++i) {
            const float s0 = acc[0][i] * 0.125f, s1 = acc[1][i] * 0.125f;
            const float s2 = acc[2][i] * 0.125f, s3 = acc[3][i] * 0.125f;
            float mx = fmaxf(fmaxf(s0, s1), fmaxf(s2, s3));
            #pragma unroll
            for (int off = 1; off < 16; off <<= 1)
                mx = fmaxf(mx, __shfl_xor(mx, off, 64));
            const float e0 = __expf(s0 - mx), e1 = __expf(s1 - mx);
            const float e2 = __expf(s2 - mx), e3 = __expf(s3 - mx);
            float sme = e0 + e1 + e2 + e3;
            #pragma unroll
            for (int off = 1; off < 16; off <<= 1)
                sme += __shfl_xor(sme, off, 64);
            const float inv = 1.f / sme;
            p[0][i] = e0 * inv; p[1][i] = e1 * inv;
            p[2][i] = e2 * inv; p[3][i] = e3 * inv;
        }
        #pragma unroll
        for (int ni = 0; ni < 4; ++ni)
            #pragma unroll
            for (int i = 0; i < 4; ++i)
                P[(w * 16 + quad * 4 + i) * 80 + ni * 16 + l15] = (_Float16)p[ni][i];

        floatx4 accv[4] = {};
        #pragma unroll
        for (int kk = 0; kk < 2; ++kk) {
            const half8_t ap = *(const half8_t*)&P[(w * 16 + l15) * 80 + kk * 32 + quad * 8];
            #pragma unroll
            for (int ni = 0; ni < 4; ++ni)
                accv[ni] = __builtin_amdgcn_mfma_f32_16x16x32_f16(
                    ap, bvf[ni][kk], accv[ni], 0, 0, 0);
        }
        #pragma unroll
        for (int ni = 0; ni < 4; ++ni)
            #pragma unroll
            for (int i = 0; i < 4; ++i) {
                const int s = srow + quad * 4 + i;
                if (s < S_)
                    CTXh[qbase + (size_t)s * D_ + ni * 16 + l15] = (_Float16)accv[ni][i];
            }
    }
}

// ---------------------------------------------------------------------------
extern "C" void kernel_launch(void* const* d_in, const int* in_sizes, int n_in,
                              void* d_out, int out_size, void* d_ws, size_t ws_size,
                              hipStream_t stream) {
    const float* X   = (const float*)d_in[0];
    const float* Wq  = (const float*)d_in[1];
    const float* bq  = (const float*)d_in[2];
    const float* Wk  = (const float*)d_in[3];
    const float* bk  = (const float*)d_in[4];
    const float* Wv  = (const float*)d_in[5];
    const float* bv  = (const float*)d_in[6];
    const float* Wo  = (const float*)d_in[7];
    const float* bo  = (const float*)d_in[8];
    const float* E_k = (const float*)d_in[9];
    const float* E_v = (const float*)d_in[10];
    float* out = (float*)d_out;

    char* p = (char*)d_ws;
    _Float16* Xh   = (_Float16*)p; p += (size_t)MPAD * D_ * 2;   // reused as CTXh
    _Float16* Tcat = (_Float16*)p; p += (size_t)3 * WSZ * 2;     // Wk,Wv,Wq
    _Float16* To   = (_Float16*)p; p += (size_t)WSZ * 2;
    _Float16* Qh   = (_Float16*)p; p += (size_t)MPAD * D_ * 2;
    _Float16* EET  = (_Float16*)p; p += (size_t)128 * KE * 2;
    float* esumK   = (float*)p;    p += 64 * sizeof(float);
    float* esumV   = (float*)p;    p += 64 * sizeof(float);
    _Float16* Ybuf = (_Float16*)p; p += (size_t)8192 * D_ * 2;
    _Float16* pk16 = (_Float16*)p; p += (size_t)4096 * D_ * 2;
    _Float16* pv16 = (_Float16*)p;

    prep_kernel<<<11810, 256, 0, stream>>>(X, Wq, Wk, Wv, Wo, E_k, E_v,
                                           Xh, Tcat, To, EET, esumK, esumV);
    y_kernel<<<768, 256, 0, stream>>>(Xh, EET, Ybuf);
    gemm_qpkv<<<1008, 256, 0, stream>>>(Xh, Ybuf, Tcat,
                                        bq, bk, bv, esumK, esumV,
                                        Qh, pk16, pv16);
    attn_kernel<<<BH_, 256, 0, stream>>>(Qh, pk16, pv16, Xh);
    gemm_o<<<1200, 256, 0, stream>>>(Xh, To, bo, out);
}